// Round 1
// baseline (212.879 us; speedup 1.0000x reference)
//
#include <hip/hip_runtime.h>
#include <hip/hip_bf16.h>

// Embedded-Gaussian non-local block, MI355X (gfx950).
// B=8, C=256, E=128, N=64*64=4096. fp32 in/out, bf16 MFMA internally.
//
// Kernel 1: QKV projection. Q,K stored [B,N,E] bf16; V stored transposed [B,E,N] bf16.
// Kernel 2: flash-style attention (no-max softmax with constant shift 15, exact by
//           softmax shift invariance; scores bounded ~25 << 88) + fused output
//           projection + bias + residual.
// LDS tiles padded (+8/+4 elems) so all ds_read_b128 fragment reads are
// conflict-free per 8-lane service group.

typedef __attribute__((ext_vector_type(8))) short s16x8;
typedef __attribute__((ext_vector_type(4))) short s16x4;
typedef __attribute__((ext_vector_type(4))) float f32x4;

#define B_ 8
#define C_ 256
#define E_ 128
#define N_ 4096

static __device__ __forceinline__ unsigned short f2bf(float f) {
    union { float f; unsigned int u; } v; v.f = f;
    return (unsigned short)((v.u + 0x7FFFu + ((v.u >> 16) & 1u)) >> 16);
}

// ---------------------------------------------------------------------------
// QKV projection: per block, one batch b and a 64-pixel tile.
// Computes Wout[E,C] @ x_b[C, ntile] (+bias) with mfma 16x16x32 bf16.
//   A-frag = weight rows (8 contiguous c per lane), streamed from global (L1/L2).
//   B-frag = x tile from LDS, stored transposed [n][c] bf16, pad 8.
// D layout (verified, guide §3): row=(lane>>4)*4+reg (= e), col=lane&15 (= n).
// ---------------------------------------------------------------------------
__global__ __launch_bounds__(256, 2) void qkv_kernel(
    const float* __restrict__ x,
    const float* __restrict__ wq, const float* __restrict__ bq,
    const float* __restrict__ wk, const float* __restrict__ bk,
    const float* __restrict__ wv, const float* __restrict__ bv,
    unsigned short* __restrict__ Q, unsigned short* __restrict__ K,
    unsigned short* __restrict__ Vt)
{
    __shared__ unsigned short xs[64 * 264];   // [n][c], pad 8

    const int tid = threadIdx.x;
    const int b  = blockIdx.x >> 6;
    const int n0 = (blockIdx.x & 63) << 6;

    // stage x tile -> LDS bf16, transposed to [n][c]
    {
        const int n  = tid & 63;
        const int c0 = tid >> 6;   // 0..3
        const float* xp = x + ((size_t)(b * C_) << 12) + n0 + n;
        for (int it = 0; it < 64; ++it) {
            const int c = it * 4 + c0;
            xs[n * 264 + c] = f2bf(xp[(size_t)c << 12]);
        }
    }
    __syncthreads();

    const int w = tid >> 6, l = tid & 63, hi = l >> 4, lx = l & 15;

    for (int idx = w; idx < 24; idx += 4) {
        const int out = idx >> 3;        // 0=q 1=k 2=v
        const int et  = idx & 7;
        const int e0  = et << 4;
        const float* W    = (out == 0) ? wq : (out == 1) ? wk : wv;
        const float* bias = (out == 0) ? bq : (out == 1) ? bk : bv;

        // A-frags: W[e0+lx][ks*32 + hi*8 + j], j=0..7
        s16x8 af[8];
        const float* wp = W + (e0 + lx) * C_ + hi * 8;
#pragma unroll
        for (int ks = 0; ks < 8; ++ks) {
            float4 f0 = *(const float4*)(wp + ks * 32);
            float4 f1 = *(const float4*)(wp + ks * 32 + 4);
            s16x8 a;
            a[0] = (short)f2bf(f0.x); a[1] = (short)f2bf(f0.y);
            a[2] = (short)f2bf(f0.z); a[3] = (short)f2bf(f0.w);
            a[4] = (short)f2bf(f1.x); a[5] = (short)f2bf(f1.y);
            a[6] = (short)f2bf(f1.z); a[7] = (short)f2bf(f1.w);
            af[ks] = a;
        }
        float bi[4];
#pragma unroll
        for (int r = 0; r < 4; ++r) bi[r] = bias[e0 + hi * 4 + r];

#pragma unroll
        for (int nt = 0; nt < 4; ++nt) {
            f32x4 acc = {0.f, 0.f, 0.f, 0.f};
#pragma unroll
            for (int ks = 0; ks < 8; ++ks) {
                s16x8 xb = *(const s16x8*)&xs[(nt * 16 + lx) * 264 + ks * 32 + hi * 8];
                acc = __builtin_amdgcn_mfma_f32_16x16x32_bf16(af[ks], xb, acc, 0, 0, 0);
            }
            const int n = n0 + nt * 16 + lx;
            if (out < 2) {
                // Q/K layout [B,N,E]: 4 consecutive e per lane -> one 8B store
                unsigned short* dst =
                    ((out == 0) ? Q : K) + ((size_t)(b * N_ + n) << 7) + e0 + hi * 4;
                s16x4 pk;
#pragma unroll
                for (int r = 0; r < 4; ++r) pk[r] = (short)f2bf(acc[r] + bi[r]);
                *(s16x4*)dst = pk;
            } else {
                // V stored transposed [B,E,N]
#pragma unroll
                for (int r = 0; r < 4; ++r)
                    Vt[((size_t)(b * E_ + e0 + hi * 4 + r) << 12) + n] =
                        f2bf(acc[r] + bi[r]);
            }
        }
    }
}

// ---------------------------------------------------------------------------
// Attention + fused output projection.
// Block: batch b = blk&7 (XCD-pins each batch's K/V into one L2), 64 q-rows,
// 4 waves x 16 q-rows. KV tiles of 64 staged in padded LDS.
// Softmax: p = exp(s - 15) accumulated without max tracking (exact).
// ---------------------------------------------------------------------------
__global__ __launch_bounds__(256, 3) void attn_kernel(
    const unsigned short* __restrict__ Q, const unsigned short* __restrict__ K,
    const unsigned short* __restrict__ Vt,
    const float* __restrict__ wo, const float* __restrict__ bo,
    const float* __restrict__ x, float* __restrict__ out)
{
    __shared__ unsigned short Ks[64 * 136];      // [kv][e], pad 8
    __shared__ unsigned short Vs[128 * 72];      // [e][kv], pad 8
    __shared__ unsigned short Ps[4 * 16 * 72];   // per-wave [q][kv], pad 8

    const int tid = threadIdx.x;
    const int b   = blockIdx.x & 7;
    const int qt  = blockIdx.x >> 3;
    const int w = tid >> 6, l = tid & 63, hi = l >> 4, lx = l & 15;
    const int n0w = qt * 64 + w * 16;

    // hoisted Q fragments: Q[n0w+lx][ks*32 + hi*8 + j]
    s16x8 qf[4];
    {
        const unsigned short* qp = Q + ((size_t)(b * N_ + n0w + lx) << 7) + hi * 8;
#pragma unroll
        for (int ks = 0; ks < 4; ++ks) qf[ks] = *(const s16x8*)(qp + ks * 32);
    }

    f32x4 feat[8];
#pragma unroll
    for (int et = 0; et < 8; ++et) feat[et] = (f32x4){0.f, 0.f, 0.f, 0.f};
    float denom[4] = {0.f, 0.f, 0.f, 0.f};

    const unsigned short* Kg = K + ((size_t)(b * N_) << 7);
    const unsigned short* Vg = Vt + ((size_t)(b * E_) << 12);

    for (int kv0 = 0; kv0 < N_; kv0 += 64) {
        __syncthreads();   // prior PV reads of Vs/Ps done before restaging
        // stage K tile [64][128] -> Ks
        {
            const int r = tid >> 4, c8 = (tid & 15) * 8;
#pragma unroll
            for (int p = 0; p < 4; ++p) {
                s16x8 v = *(const s16x8*)(Kg + (size_t)(kv0 + p * 16 + r) * 128 + c8);
                *(s16x8*)&Ks[(p * 16 + r) * 136 + c8] = v;
            }
        }
        // stage V tile [128 e][64 kv] -> Vs (8B granules, conflict-free)
        {
            const int e = tid >> 4, c4 = (tid & 15) * 4;
#pragma unroll
            for (int p = 0; p < 8; ++p) {
                s16x4 v = *(const s16x4*)(Vg + ((size_t)(p * 16 + e) << 12) + kv0 + c4);
                *(s16x4*)&Vs[(p * 16 + e) * 72 + c4] = v;
            }
        }
        __syncthreads();

        // S = Q K^T : per wave 16 q x 64 kv, D[row=q(4hi+r)][col=kv(lx)]
        f32x4 sacc[4];
#pragma unroll
        for (int t = 0; t < 4; ++t) {
            f32x4 acc = {0.f, 0.f, 0.f, 0.f};
#pragma unroll
            for (int ks = 0; ks < 4; ++ks) {
                s16x8 kb = *(const s16x8*)&Ks[(t * 16 + lx) * 136 + ks * 32 + hi * 8];
                acc = __builtin_amdgcn_mfma_f32_16x16x32_bf16(qf[ks], kb, acc, 0, 0, 0);
            }
            sacc[t] = acc;
        }

        // p = exp(s-15); row sums; write P (bf16) to per-wave LDS
        float psum[4] = {0.f, 0.f, 0.f, 0.f};
#pragma unroll
        for (int t = 0; t < 4; ++t) {
#pragma unroll
            for (int r = 0; r < 4; ++r) {
                float p = __expf(sacc[t][r] - 15.f);
                psum[r] += p;
                Ps[(w * 16 + hi * 4 + r) * 72 + t * 16 + lx] = f2bf(p);
            }
        }
#pragma unroll
        for (int r = 0; r < 4; ++r) {
            float s = psum[r];
            s += __shfl_xor(s, 1);  s += __shfl_xor(s, 2);
            s += __shfl_xor(s, 4);  s += __shfl_xor(s, 8);
            denom[r] += s;
        }
        __syncthreads();   // P visible; also orders Ks reads before next restage

        // PV: feat[16 q x 128 e] += P[16x64] @ V[64x128]
        s16x8 pa[2];
#pragma unroll
        for (int ks = 0; ks < 2; ++ks)
            pa[ks] = *(const s16x8*)&Ps[(w * 16 + lx) * 72 + ks * 32 + hi * 8];
#pragma unroll
        for (int et = 0; et < 8; ++et) {
#pragma unroll
            for (int ks = 0; ks < 2; ++ks) {
                s16x8 vb = *(const s16x8*)&Vs[(et * 16 + lx) * 72 + ks * 32 + hi * 8];
                feat[et] = __builtin_amdgcn_mfma_f32_16x16x32_bf16(pa[ks], vb, feat[et], 0, 0, 0);
            }
        }
    }

    __syncthreads();
    // normalize and park feat (bf16) in Ks region rows [16w, 16w+16)
    float inv[4];
#pragma unroll
    for (int r = 0; r < 4; ++r) inv[r] = 1.f / denom[r];
#pragma unroll
    for (int et = 0; et < 8; ++et)
#pragma unroll
        for (int r = 0; r < 4; ++r)
            Ks[(w * 16 + hi * 4 + r) * 136 + et * 16 + lx] =
                f2bf(feat[et][r] * inv[r]);
    __syncthreads();

    // A-frags of feat for output projection
    s16x8 fa[4];
#pragma unroll
    for (int ks = 0; ks < 4; ++ks)
        fa[ks] = *(const s16x8*)&Ks[(w * 16 + lx) * 136 + ks * 32 + hi * 8];

    // out[n][c] = feat[n] . wo[c] + bo[c] + x[b][c][n]
    const size_t xbase = (size_t)(b * C_) << 12;
#pragma unroll 1
    for (int ct = 0; ct < 16; ++ct) {
        const int c = ct * 16 + lx;
        const float* wp = wo + c * 128 + hi * 8;
        f32x4 acc = {0.f, 0.f, 0.f, 0.f};
#pragma unroll
        for (int ks = 0; ks < 4; ++ks) {
            float4 f0 = *(const float4*)(wp + ks * 32);
            float4 f1 = *(const float4*)(wp + ks * 32 + 4);
            s16x8 wb;
            wb[0] = (short)f2bf(f0.x); wb[1] = (short)f2bf(f0.y);
            wb[2] = (short)f2bf(f0.z); wb[3] = (short)f2bf(f0.w);
            wb[4] = (short)f2bf(f1.x); wb[5] = (short)f2bf(f1.y);
            wb[6] = (short)f2bf(f1.z); wb[7] = (short)f2bf(f1.w);
            acc = __builtin_amdgcn_mfma_f32_16x16x32_bf16(fa[ks], wb, acc, 0, 0, 0);
        }
        const float bc = bo[c];
#pragma unroll
        for (int r = 0; r < 4; ++r) {
            const size_t off = xbase + ((size_t)c << 12) + (size_t)(n0w + hi * 4 + r);
            out[off] = acc[r] + bc + x[off];
        }
    }
}

extern "C" void kernel_launch(void* const* d_in, const int* in_sizes, int n_in,
                              void* d_out, int out_size, void* d_ws, size_t ws_size,
                              hipStream_t stream) {
    (void)in_sizes; (void)n_in; (void)out_size; (void)ws_size;
    const float* x  = (const float*)d_in[0];
    const float* wq = (const float*)d_in[1];
    const float* bq = (const float*)d_in[2];
    const float* wk = (const float*)d_in[3];
    const float* bk = (const float*)d_in[4];
    const float* wv = (const float*)d_in[5];
    const float* bv = (const float*)d_in[6];
    const float* wo = (const float*)d_in[7];
    const float* bo = (const float*)d_in[8];

    unsigned short* Q  = (unsigned short*)d_ws;                 // [B,N,E] bf16
    unsigned short* K  = Q + (size_t)B_ * N_ * E_;              // [B,N,E] bf16
    unsigned short* Vt = K + (size_t)B_ * N_ * E_;              // [B,E,N] bf16

    qkv_kernel<<<dim3(B_ * (N_ / 64)), dim3(256), 0, stream>>>(
        x, wq, bq, wk, bk, wv, bv, Q, K, Vt);
    attn_kernel<<<dim3(B_ * (N_ / 64)), dim3(256), 0, stream>>>(
        Q, K, Vt, wo, bo, x, (float*)d_out);
}

// Round 2
// 187.069 us; speedup vs baseline: 1.1380x; 1.1380x over previous
//
#include <hip/hip_runtime.h>
#include <hip/hip_bf16.h>

// Embedded-Gaussian non-local block, MI355X (gfx950).
// B=8, C=256, E=128, N=64*64=4096. fp32 in/out, bf16 MFMA internally.
//
// Kernel 1: QKV projection. Q,K stored [B,N,E] bf16; V stored transposed [B,E,N] bf16.
// Kernel 2: attn_partial: flash-style attention with fixed-shift softmax
//           (p = exp(s-15), exact by shift invariance, no max tracking).
//           kv range split 4-ways across blocks; each block writes
//           UNNORMALIZED feat partials (bf16) + denom partials (f32) -- these
//           combine by plain addition across slices.
//           Geometry: 1024 blocks = 8 b x 32 qtiles(128q) x 4 kv-slices,
//           4 waves x 32 q-rows each, kv tiles of 64 double-barrier staged.
// Kernel 3: combine: sum 4 partials, normalize, out-projection (MFMA) + bias
//           + residual.
// All LDS b128 fragment reads use strides = 16B*odd (272B, 144B) ->
// 8 lanes/quad-group, minimum service cycles (conflict-free).

typedef __attribute__((ext_vector_type(8))) short s16x8;
typedef __attribute__((ext_vector_type(4))) short s16x4;
typedef __attribute__((ext_vector_type(4))) float f32x4;

#define B_ 8
#define C_ 256
#define E_ 128
#define N_ 4096
#define SHIFT 15.0f

static __device__ __forceinline__ unsigned short f2bf(float f) {
    union { float f; unsigned int u; } v; v.f = f;
    return (unsigned short)((v.u + 0x7FFFu + ((v.u >> 16) & 1u)) >> 16);
}
static __device__ __forceinline__ float bf2f(unsigned short h) {
    union { unsigned int u; float f; } v; v.u = ((unsigned int)h) << 16;
    return v.f;
}

// ---------------------------------------------------------------------------
// QKV projection (unchanged from round 1; ~14us).
// ---------------------------------------------------------------------------
__global__ __launch_bounds__(256, 2) void qkv_kernel(
    const float* __restrict__ x,
    const float* __restrict__ wq, const float* __restrict__ bq,
    const float* __restrict__ wk, const float* __restrict__ bk,
    const float* __restrict__ wv, const float* __restrict__ bv,
    unsigned short* __restrict__ Q, unsigned short* __restrict__ K,
    unsigned short* __restrict__ Vt)
{
    __shared__ unsigned short xs[64 * 264];   // [n][c], pad 8

    const int tid = threadIdx.x;
    const int b  = blockIdx.x >> 6;
    const int n0 = (blockIdx.x & 63) << 6;

    {
        const int n  = tid & 63;
        const int c0 = tid >> 6;   // 0..3
        const float* xp = x + ((size_t)(b * C_) << 12) + n0 + n;
        for (int it = 0; it < 64; ++it) {
            const int c = it * 4 + c0;
            xs[n * 264 + c] = f2bf(xp[(size_t)c << 12]);
        }
    }
    __syncthreads();

    const int w = tid >> 6, l = tid & 63, hi = l >> 4, lx = l & 15;

    for (int idx = w; idx < 24; idx += 4) {
        const int out = idx >> 3;        // 0=q 1=k 2=v
        const int et  = idx & 7;
        const int e0  = et << 4;
        const float* W    = (out == 0) ? wq : (out == 1) ? wk : wv;
        const float* bias = (out == 0) ? bq : (out == 1) ? bk : bv;

        s16x8 af[8];
        const float* wp = W + (e0 + lx) * C_ + hi * 8;
#pragma unroll
        for (int ks = 0; ks < 8; ++ks) {
            float4 f0 = *(const float4*)(wp + ks * 32);
            float4 f1 = *(const float4*)(wp + ks * 32 + 4);
            s16x8 a;
            a[0] = (short)f2bf(f0.x); a[1] = (short)f2bf(f0.y);
            a[2] = (short)f2bf(f0.z); a[3] = (short)f2bf(f0.w);
            a[4] = (short)f2bf(f1.x); a[5] = (short)f2bf(f1.y);
            a[6] = (short)f2bf(f1.z); a[7] = (short)f2bf(f1.w);
            af[ks] = a;
        }
        float bi[4];
#pragma unroll
        for (int r = 0; r < 4; ++r) bi[r] = bias[e0 + hi * 4 + r];

#pragma unroll
        for (int nt = 0; nt < 4; ++nt) {
            f32x4 acc = {0.f, 0.f, 0.f, 0.f};
#pragma unroll
            for (int ks = 0; ks < 8; ++ks) {
                s16x8 xb = *(const s16x8*)&xs[(nt * 16 + lx) * 264 + ks * 32 + hi * 8];
                acc = __builtin_amdgcn_mfma_f32_16x16x32_bf16(af[ks], xb, acc, 0, 0, 0);
            }
            const int n = n0 + nt * 16 + lx;
            if (out < 2) {
                unsigned short* dst =
                    ((out == 0) ? Q : K) + ((size_t)(b * N_ + n) << 7) + e0 + hi * 4;
                s16x4 pk;
#pragma unroll
                for (int r = 0; r < 4; ++r) pk[r] = (short)f2bf(acc[r] + bi[r]);
                *(s16x4*)dst = pk;
            } else {
#pragma unroll
                for (int r = 0; r < 4; ++r)
                    Vt[((size_t)(b * E_ + e0 + hi * 4 + r) << 12) + n] =
                        f2bf(acc[r] + bi[r]);
            }
        }
    }
}

// ---------------------------------------------------------------------------
// Attention partial kernel.
// blockIdx: b = blk&7 (XCD pin), idx = blk>>3: sl = idx>>5 (kv slice 0..3),
// qt = idx&31 (q-tile of 128). Wave w handles q rows qt*128 + w*32 + [0,32).
// Writes featP[sl][b][qt][128q][128e] bf16 (unnormalized) and
// denomP[sl][b][qt][128q] f32.
// ---------------------------------------------------------------------------
__global__ __launch_bounds__(256, 2) void attn_partial(
    const unsigned short* __restrict__ Q, const unsigned short* __restrict__ K,
    const unsigned short* __restrict__ Vt,
    unsigned short* __restrict__ featP, float* __restrict__ denomP)
{
    __shared__ unsigned short Ks[64 * 136];      // [kv][e], stride 272B (17*16B)
    __shared__ unsigned short Vs[128 * 72];      // [e][kv], stride 144B (9*16B)
    __shared__ unsigned short Ps[4][32 * 72];    // per-wave [q][kv], stride 144B

    const int tid = threadIdx.x;
    const int b   = blockIdx.x & 7;
    const int idx = blockIdx.x >> 3;
    const int sl  = idx >> 5;      // kv slice
    const int qt  = idx & 31;      // q tile (128 rows)
    const int w = tid >> 6, l = tid & 63, hi = l >> 4, lx = l & 15;

    // hoisted Q fragments: 2 qf x 4 ks, lane holds Q[q=qf*16+lx][ks*32+hi*8 ..+8]
    s16x8 qA[2][4];
#pragma unroll
    for (int qf = 0; qf < 2; ++qf) {
        const unsigned short* qp =
            Q + ((size_t)(b * N_ + qt * 128 + w * 32 + qf * 16 + lx) << 7) + hi * 8;
#pragma unroll
        for (int ks = 0; ks < 4; ++ks) qA[qf][ks] = *(const s16x8*)(qp + ks * 32);
    }

    f32x4 feat[2][8];
#pragma unroll
    for (int qf = 0; qf < 2; ++qf)
#pragma unroll
        for (int ef = 0; ef < 8; ++ef) feat[qf][ef] = (f32x4){0.f, 0.f, 0.f, 0.f};
    float dAcc[8];
#pragma unroll
    for (int i = 0; i < 8; ++i) dAcc[i] = 0.f;

    const unsigned short* Kg = K + ((size_t)(b * N_) << 7);
    const unsigned short* Vg = Vt + ((size_t)(b * E_) << 12);
    const int kvBase = sl << 10;

    for (int it = 0; it < 16; ++it) {
        const int kv0 = kvBase + it * 64;
        __syncthreads();   // prior iter's LDS reads complete before restage
        // stage K tile [64 kv][128 e]: 256 thr x 4 chunks of 16B
        {
            const int row = tid & 63, cb = (tid >> 6) * 4;
            const unsigned short* src = Kg + (size_t)(kv0 + row) * 128 + cb * 8;
            unsigned short* dst = &Ks[row * 136 + cb * 8];
#pragma unroll
            for (int i = 0; i < 4; ++i)
                *(s16x8*)(dst + i * 8) = *(const s16x8*)(src + i * 8);
        }
        // stage V tile [128 e][64 kv]: 256 thr x 4 chunks of 16B
        {
            const int e = tid & 127, cb = (tid >> 7) * 4;
            const unsigned short* src = Vg + ((size_t)e << 12) + kv0 + cb * 8;
            unsigned short* dst = &Vs[e * 72 + cb * 8];
#pragma unroll
            for (int i = 0; i < 4; ++i)
                *(s16x8*)(dst + i * 8) = *(const s16x8*)(src + i * 8);
        }
        __syncthreads();

        // QK^T: 32q x 64kv per wave; K frag read once per (kvf,ks)
#pragma unroll
        for (int kvf = 0; kvf < 4; ++kvf) {
            f32x4 s0 = {0.f, 0.f, 0.f, 0.f}, s1 = {0.f, 0.f, 0.f, 0.f};
#pragma unroll
            for (int ks = 0; ks < 4; ++ks) {
                s16x8 kb = *(const s16x8*)&Ks[(kvf * 16 + lx) * 136 + ks * 32 + hi * 8];
                s0 = __builtin_amdgcn_mfma_f32_16x16x32_bf16(qA[0][ks], kb, s0, 0, 0, 0);
                s1 = __builtin_amdgcn_mfma_f32_16x16x32_bf16(qA[1][ks], kb, s1, 0, 0, 0);
            }
            // p = exp(s - SHIFT); accumulate denom; P -> per-wave LDS [q][kv]
            unsigned short* pw = &Ps[w][0];
#pragma unroll
            for (int r = 0; r < 4; ++r) {
                float p0 = __expf(s0[r] - SHIFT);
                float p1 = __expf(s1[r] - SHIFT);
                dAcc[r]     += p0;
                dAcc[4 + r] += p1;
                pw[(hi * 4 + r) * 72      + kvf * 16 + lx] = f2bf(p0);
                pw[(16 + hi * 4 + r) * 72 + kvf * 16 + lx] = f2bf(p1);
            }
        }
        // PV: feat[32q x 128e] += P[32x64] @ V[64x128] (P is wave-private, no barrier)
#pragma unroll
        for (int ks = 0; ks < 2; ++ks) {
            s16x8 pa0 = *(const s16x8*)&Ps[w][(lx)      * 72 + ks * 32 + hi * 8];
            s16x8 pa1 = *(const s16x8*)&Ps[w][(16 + lx) * 72 + ks * 32 + hi * 8];
#pragma unroll
            for (int ef = 0; ef < 8; ++ef) {
                s16x8 vb = *(const s16x8*)&Vs[(ef * 16 + lx) * 72 + ks * 32 + hi * 8];
                feat[0][ef] = __builtin_amdgcn_mfma_f32_16x16x32_bf16(pa0, vb, feat[0][ef], 0, 0, 0);
                feat[1][ef] = __builtin_amdgcn_mfma_f32_16x16x32_bf16(pa1, vb, feat[1][ef], 0, 0, 0);
            }
        }
    }

    // denom: reduce over kv lanes (lx dimension)
#pragma unroll
    for (int i = 0; i < 8; ++i) {
        float v = dAcc[i];
        v += __shfl_xor(v, 1); v += __shfl_xor(v, 2);
        v += __shfl_xor(v, 4); v += __shfl_xor(v, 8);
        dAcc[i] = v;
    }
    const size_t tileBase = (size_t)((sl * 8 + b) * 32 + qt);
    float* dP = denomP + (tileBase << 7) + w * 32;
    if (lx == 0) {
#pragma unroll
        for (int qf = 0; qf < 2; ++qf)
#pragma unroll
            for (int r = 0; r < 4; ++r)
                dP[qf * 16 + hi * 4 + r] = dAcc[qf * 4 + r];
    }
    // featP: unnormalized, bf16
    unsigned short* fP = featP + (tileBase << 14) + ((size_t)(w * 32) << 7);
#pragma unroll
    for (int qf = 0; qf < 2; ++qf)
#pragma unroll
        for (int ef = 0; ef < 8; ++ef)
#pragma unroll
            for (int r = 0; r < 4; ++r)
                fP[(qf * 16 + hi * 4 + r) * 128 + ef * 16 + lx] =
                    f2bf(feat[qf][ef][r]);
}

// ---------------------------------------------------------------------------
// Combine: sum 4 kv-slice partials, normalize, out-projection + bias + residual.
// grid: 8 b x 64 n-tiles of 64q; 4 waves x 16q for the epilogue GEMM.
// ---------------------------------------------------------------------------
__global__ __launch_bounds__(256, 2) void combine_kernel(
    const unsigned short* __restrict__ featP, const float* __restrict__ denomP,
    const float* __restrict__ wo, const float* __restrict__ bo,
    const float* __restrict__ x, float* __restrict__ out)
{
    __shared__ unsigned short fs[64 * 136];   // [q][e], stride 272B

    const int tid = threadIdx.x;
    const int b  = blockIdx.x & 7;
    const int nt = blockIdx.x >> 3;          // 0..63
    const int qt = nt >> 1, qoff = (nt & 1) * 64;

    // sum partials + normalize -> fs (bf16)
    {
        const int q = tid >> 2, eb = (tid & 3) * 32;
        const size_t base =
            ((size_t)(b * 32 + qt) << 14) + ((size_t)(qoff + q) << 7) + eb;
        const size_t dbase = ((size_t)(b * 32 + qt) << 7) + qoff + q;
        float den = 0.f;
#pragma unroll
        for (int s = 0; s < 4; ++s) den += denomP[((size_t)s << 15) + dbase];
        const float inv = 1.f / den;
#pragma unroll
        for (int e8 = 0; e8 < 4; ++e8) {
            float acc[8];
#pragma unroll
            for (int j = 0; j < 8; ++j) acc[j] = 0.f;
#pragma unroll
            for (int s = 0; s < 4; ++s) {
                s16x8 v = *(const s16x8*)(featP + ((size_t)s << 22) + base + e8 * 8);
#pragma unroll
                for (int j = 0; j < 8; ++j) acc[j] += bf2f((unsigned short)v[j]);
            }
            s16x8 o;
#pragma unroll
            for (int j = 0; j < 8; ++j) o[j] = (short)f2bf(acc[j] * inv);
            *(s16x8*)&fs[q * 136 + eb + e8 * 8] = o;
        }
    }
    __syncthreads();

    const int w = tid >> 6, l = tid & 63, hi = l >> 4, lx = l & 15;
    const int n0w = nt * 64 + w * 16;

    s16x8 fa[4];
#pragma unroll
    for (int ks = 0; ks < 4; ++ks)
        fa[ks] = *(const s16x8*)&fs[(w * 16 + lx) * 136 + ks * 32 + hi * 8];

    const size_t xbase = (size_t)(b * C_) << 12;
#pragma unroll 1
    for (int ct = 0; ct < 16; ++ct) {
        const int c = ct * 16 + lx;
        const float* wp = wo + c * 128 + hi * 8;
        f32x4 acc = {0.f, 0.f, 0.f, 0.f};
#pragma unroll
        for (int ks = 0; ks < 4; ++ks) {
            float4 f0 = *(const float4*)(wp + ks * 32);
            float4 f1 = *(const float4*)(wp + ks * 32 + 4);
            s16x8 wb;
            wb[0] = (short)f2bf(f0.x); wb[1] = (short)f2bf(f0.y);
            wb[2] = (short)f2bf(f0.z); wb[3] = (short)f2bf(f0.w);
            wb[4] = (short)f2bf(f1.x); wb[5] = (short)f2bf(f1.y);
            wb[6] = (short)f2bf(f1.z); wb[7] = (short)f2bf(f1.w);
            acc = __builtin_amdgcn_mfma_f32_16x16x32_bf16(fa[ks], wb, acc, 0, 0, 0);
        }
        const float bc = bo[c];
#pragma unroll
        for (int r = 0; r < 4; ++r) {
            const size_t off = xbase + ((size_t)c << 12) + (size_t)(n0w + hi * 4 + r);
            out[off] = acc[r] + bc + x[off];
        }
    }
}

extern "C" void kernel_launch(void* const* d_in, const int* in_sizes, int n_in,
                              void* d_out, int out_size, void* d_ws, size_t ws_size,
                              hipStream_t stream) {
    (void)in_sizes; (void)n_in; (void)out_size; (void)ws_size;
    const float* x  = (const float*)d_in[0];
    const float* wq = (const float*)d_in[1];
    const float* bq = (const float*)d_in[2];
    const float* wk = (const float*)d_in[3];
    const float* bk = (const float*)d_in[4];
    const float* wv = (const float*)d_in[5];
    const float* bv = (const float*)d_in[6];
    const float* wo = (const float*)d_in[7];
    const float* bo = (const float*)d_in[8];

    unsigned short* Q  = (unsigned short*)d_ws;                 // [B,N,E] bf16, 4M elems
    unsigned short* K  = Q + (size_t)B_ * N_ * E_;              // [B,N,E] bf16
    unsigned short* Vt = K + (size_t)B_ * N_ * E_;              // [B,E,N] bf16
    unsigned short* featP = Vt + (size_t)B_ * N_ * E_;          // [4][B][32][128][128] bf16
    float* denomP = (float*)(featP + (size_t)4 * B_ * N_ * E_); // [4][B][32][128] f32

    qkv_kernel<<<dim3(B_ * (N_ / 64)), dim3(256), 0, stream>>>(
        x, wq, bq, wk, bk, wv, bv, Q, K, Vt);
    attn_partial<<<dim3(B_ * 32 * 4), dim3(256), 0, stream>>>(
        Q, K, Vt, featP, denomP);
    combine_kernel<<<dim3(B_ * 64), dim3(256), 0, stream>>>(
        featP, denomP, wo, bo, x, (float*)d_out);
}